// Round 9
// baseline (2301.812 us; speedup 1.0000x reference)
//
#include <hip/hip_runtime.h>
#include <hip/hip_bf16.h>
#include <cmath>

#define D_MODEL 128
#define NUM_HEAD 4
#define HEAD_DIM 32
#define SEQ 4096
#define BATCH 2
#define QTILE 64   // q-rows per tile (one per lane, G=1 -> no spill)
#define NW 8       // waves per attention block (k-split factor)
#define CHUNK 8    // k's per softmax-rescale chunk; (qt+1)*8 divisible by 8
#define RROWS 32   // token rows per projection block

__device__ __forceinline__ float tof(float x) { return x; }
__device__ __forceinline__ float tof(__hip_bfloat16 x) { return __bfloat162float(x); }
__device__ __forceinline__ void storef(float* p, size_t i, float v) { p[i] = v; }
__device__ __forceinline__ void storef(__hip_bfloat16* p, size_t i, float v) { p[i] = __float2bfloat16(v); }
__device__ __forceinline__ float4 load4(const float* p) { return *(const float4*)p; }
__device__ __forceinline__ float4 load4(const __hip_bfloat16* p) {
    return make_float4(tof(p[0]), tof(p[1]), tof(p[2]), tof(p[3]));
}

// ---------------------------------------------------------------------------
// Kernel 0: dtype detector (f32 vs bf16 inputs), unchanged (passes since R3).
// ---------------------------------------------------------------------------
__global__ void detect_kernel(const unsigned short* __restrict__ w, int* __restrict__ flag)
{
    const int t = threadIdx.x;   // 64 threads
    int weird = 0;
#pragma unroll
    for (int j = 0; j < 4; ++j) {
        const unsigned short v = w[(t * 4 + j) * 2 + 1];
        const float x = __uint_as_float((unsigned)v << 16);
        const float a = fabsf(x);
        if (a > 1e20f || (a > 0.f && a < 1e-20f)) weird++;
    }
#pragma unroll
    for (int off = 32; off; off >>= 1) weird += __shfl_xor(weird, off);
    if (t == 0) *flag = (weird < 32) ? 1 : 0;
}

// ---------------------------------------------------------------------------
// Kernel 1: x = embedding[seq] + PE;  Q/K/V = x @ W^T  (f32 to workspace)
// float4 weight loads (4x fewer strided VMEM instr than R8's scalar), PE via
// one f64 sincos + incremental complex rotation (6 f64 ops/row vs sincos/row).
// ---------------------------------------------------------------------------
template <typename T>
__device__ __forceinline__ void qkv_body(
    const int* __restrict__ seq, const T* __restrict__ emb,
    const T* __restrict__ wq, const T* __restrict__ wk, const T* __restrict__ wv,
    float* __restrict__ Q, float* __restrict__ K, float* __restrict__ V)
{
    const int e = threadIdx.x;               // 0..127 output dim
    const int r0 = blockIdx.x * RROWS;
    __shared__ __align__(16) float xs[RROWS][D_MODEL];

    // PE by rotation: angle(r) = (s0+r)*inv; rotate (cos,sin) by inv per row.
    {
        const int i = e >> 1;
        const double inv = 1.0 / pow(10000.0, (double)i / 64.0);
        const int s0 = r0 & (SEQ - 1);       // blocks never straddle batch edge
        double c = cos((double)s0 * inv);
        double s = sin((double)s0 * inv);
        const double cd = cos(inv), sd = sin(inv);
        const bool odd = (e & 1);
#pragma unroll 4
        for (int r = 0; r < RROWS; ++r) {
            const float pe = (float)(odd ? c : s);
            xs[r][e] = tof(emb[(size_t)seq[r0 + r] * D_MODEL + e]) + pe;
            const double cn = c * cd - s * sd;
            s = s * cd + c * sd;
            c = cn;
        }
    }
    __syncthreads();

    const T* wqr = wq + e * D_MODEL;
    const T* wkr = wk + e * D_MODEL;
    const T* wvr = wv + e * D_MODEL;
    float aq[RROWS], ak[RROWS], av[RROWS];
#pragma unroll
    for (int r = 0; r < RROWS; ++r) { aq[r] = 0.f; ak[r] = 0.f; av[r] = 0.f; }

    for (int c = 0; c < 32; ++c) {
        const float4 wq4 = load4(wqr + 4 * c);
        const float4 wk4 = load4(wkr + 4 * c);
        const float4 wv4 = load4(wvr + 4 * c);
#pragma unroll
        for (int r = 0; r < RROWS; ++r) {
            const float4 x4 = *(const float4*)&xs[r][4*c];   // wave-uniform broadcast
            aq[r] += x4.x*wq4.x + x4.y*wq4.y + x4.z*wq4.z + x4.w*wq4.w;
            ak[r] += x4.x*wk4.x + x4.y*wk4.y + x4.z*wk4.z + x4.w*wk4.w;
            av[r] += x4.x*wv4.x + x4.y*wv4.y + x4.z*wv4.z + x4.w*wv4.w;
        }
    }
#pragma unroll
    for (int r = 0; r < RROWS; ++r) {
        const size_t o = (size_t)(r0 + r) * D_MODEL + e;
        Q[o] = aq[r]; K[o] = ak[r]; V[o] = av[r];
    }
}

__global__ __launch_bounds__(128) void qkv_kernel(
    const int* __restrict__ seq, const void* emb,
    const void* wq, const void* wk, const void* wv,
    float* __restrict__ Q, float* __restrict__ K, float* __restrict__ V,
    const int* __restrict__ flag)
{
    if (*flag)
        qkv_body<float>(seq, (const float*)emb, (const float*)wq,
                        (const float*)wk, (const float*)wv, Q, K, V);
    else
        qkv_body<__hip_bfloat16>(seq, (const __hip_bfloat16*)emb, (const __hip_bfloat16*)wq,
                                 (const __hip_bfloat16*)wk, (const __hip_bfloat16*)wv, Q, K, V);
}

// ---------------------------------------------------------------------------
// Kernel 2: attention, G=1 (qv[32], ov[32], m, l per lane; VGPR=128 no-spill,
// R8-verified). K/V rows via VMEM broadcast float4 (opaque-zero-tainted
// pointer prevents s_load regression). R9 change: UNPAIRED grid - one q-tile
// per block, 512 blocks = 2/CU = 4 waves/SIMD (R8's paired 256 blocks capped
// at 2 waves/SIMD -> load-latency bound at 26% VALUBusy). LPT order: qt
// descending in dispatch order; bh on fast axis so round-robin XCD = bh
// (each XCD's L2 holds its bh's 2MB of K+V). Dynamic refill eats the tail.
// ---------------------------------------------------------------------------
__device__ __forceinline__ void attn_tile(
    int qt, int wid, int lane, int tid,
    const float* __restrict__ Qh, const float* __restrict__ Kh,
    const float* __restrict__ Vh, float* __restrict__ Oh,
    float (*part)[QTILE][10])
{
    const int row = qt * QTILE + lane;

    float qv[32];
#pragma unroll
    for (int j4 = 0; j4 < 8; ++j4) {
        const float4 a = *(const float4*)(Qh + (size_t)row * HEAD_DIM + 4 * j4);
        qv[4*j4] = a.x; qv[4*j4+1] = a.y; qv[4*j4+2] = a.z; qv[4*j4+3] = a.w;
    }

    float ov[32];
#pragma unroll
    for (int j = 0; j < 32; ++j) ov[j] = 0.f;
    float m = 0.f, l = 0.f;
    const float scale = 0.17677669529663687f;   // 1/sqrt(32)

    const int share = (qt + 1) * (QTILE / NW);  // = (qt+1)*8, multiple of CHUNK
    const int kbeg  = wid * share;
    const int kend  = kbeg + share;

    for (int k0 = kbeg; k0 < kend; k0 += CHUNK) {
        float p[CHUNK];
        float cm = m;
#pragma unroll
        for (int i = 0; i < CHUNK; ++i) {
            const int k = k0 + i;
            const float* kr = Kh + (size_t)k * HEAD_DIM;
            float sc = 0.f;
#pragma unroll
            for (int j4 = 0; j4 < 8; ++j4) {
                const float4 kk = *(const float4*)(kr + 4 * j4);
                sc += qv[4*j4]*kk.x + qv[4*j4+1]*kk.y + qv[4*j4+2]*kk.z + qv[4*j4+3]*kk.w;
            }
            sc = fabsf(sc) * scale;
            p[i] = (k <= row) ? sc : -1.f;      // causal mask (head-space)
            cm = fmaxf(cm, p[i]);
        }
        const float alpha = __expf(m - cm);     // == 1 when max unchanged
        l *= alpha; m = cm;
#pragma unroll
        for (int j = 0; j < 32; ++j) ov[j] *= alpha;
#pragma unroll
        for (int i = 0; i < CHUNK; ++i) {
            const int k = k0 + i;
            const float* vr = Vh + (size_t)k * HEAD_DIM;
            const float e0 = (p[i] >= 0.f) ? __expf(p[i] - m) : 0.f;
            l += e0;
#pragma unroll
            for (int j4 = 0; j4 < 8; ++j4) {
                const float4 vv = *(const float4*)(vr + 4 * j4);
                ov[4*j4]   += e0 * vv.x; ov[4*j4+1] += e0 * vv.y;
                ov[4*j4+2] += e0 * vv.z; ov[4*j4+3] += e0 * vv.w;
            }
        }
    }

    // combine the 8 per-wave partials; 4 passes of 8 dims; LDS = 20.5KB
#pragma unroll
    for (int pass = 0; pass < 4; ++pass) {
        __syncthreads();
#pragma unroll
        for (int j = 0; j < 8; ++j) part[wid][lane][j] = ov[pass * 8 + j];
        part[wid][lane][8] = m;
        part[wid][lane][9] = l;
        __syncthreads();
        {
            const int r = tid >> 3;        // 0..63
            const int j = tid & 7;
            float M = 0.f;
#pragma unroll
            for (int w = 0; w < NW; ++w) M = fmaxf(M, part[w][r][8]);
            float lsum = 0.f, osum = 0.f;
#pragma unroll
            for (int w = 0; w < NW; ++w) {
                const float a = __expf(part[w][r][8] - M);
                lsum += a * part[w][r][9];
                osum += a * part[w][r][j];
            }
            Oh[(size_t)(qt * QTILE + r) * HEAD_DIM + pass * 8 + j] = osum / lsum;
        }
    }
}

__global__ __launch_bounds__(512, 4) void attn_kernel(
    const float* __restrict__ Q, const float* __restrict__ K,
    const float* __restrict__ V, float* __restrict__ O)
{
    const int bh = blockIdx.x;              // fast axis -> XCD = bh
    const int qt = 63 - blockIdx.y;         // big tiles dispatched first (LPT)
    const size_t base = (size_t)(bh >> 2) * SEQ * D_MODEL + (size_t)(bh & 3) * SEQ * HEAD_DIM;
    const float* Qh = Q + base;
    float*       Oh = O + base;

    int lzero;                               // opaque 0 in a VGPR
    asm volatile("v_mov_b32 %0, 0" : "=v"(lzero));
    const float* Kh = K + base + lzero;      // VGPR-tainted -> VMEM loads
    const float* Vh = V + base + lzero;

    const int tid  = threadIdx.x;
    const int wid  = __builtin_amdgcn_readfirstlane(tid >> 6);
    const int lane = tid & 63;

    __shared__ float part[NW][QTILE][10];

    attn_tile(qt, wid, lane, tid, Qh, Kh, Vh, Oh, part);
}

// ---------------------------------------------------------------------------
// Kernel 3: out = att @ Wo^T  (32-row weight reuse, float4 weight loads)
// ---------------------------------------------------------------------------
template <typename T>
__device__ __forceinline__ void out_proj_body(
    const float* __restrict__ att, const T* __restrict__ wo, T* __restrict__ out)
{
    const int e = threadIdx.x;
    const int r0 = blockIdx.x * RROWS;
    __shared__ __align__(16) float xs[RROWS][D_MODEL];
#pragma unroll 4
    for (int r = 0; r < RROWS; ++r)
        xs[r][e] = att[(size_t)(r0 + r) * D_MODEL + e];
    __syncthreads();

    const T* wr = wo + e * D_MODEL;
    float acc[RROWS];
#pragma unroll
    for (int r = 0; r < RROWS; ++r) acc[r] = 0.f;
    for (int c = 0; c < 32; ++c) {
        const float4 w4 = load4(wr + 4 * c);
#pragma unroll
        for (int r = 0; r < RROWS; ++r) {
            const float4 x4 = *(const float4*)&xs[r][4*c];
            acc[r] += x4.x*w4.x + x4.y*w4.y + x4.z*w4.z + x4.w*w4.w;
        }
    }
#pragma unroll
    for (int r = 0; r < RROWS; ++r)
        storef(out, (size_t)(r0 + r) * D_MODEL + e, acc[r]);
}

__global__ __launch_bounds__(128) void out_proj_kernel(
    const float* __restrict__ att, const void* wo, void* out,
    const int* __restrict__ flag)
{
    if (*flag)
        out_proj_body<float>(att, (const float*)wo, (float*)out);
    else
        out_proj_body<__hip_bfloat16>(att, (const __hip_bfloat16*)wo, (__hip_bfloat16*)out);
}

extern "C" void kernel_launch(void* const* d_in, const int* in_sizes, int n_in,
                              void* d_out, int out_size, void* d_ws, size_t ws_size,
                              hipStream_t stream) {
    const int* seq = (const int*)d_in[0];
    const void* emb = d_in[1];
    const void* wq  = d_in[2];
    const void* wk  = d_in[3];
    const void* wv  = d_in[4];
    const void* wo  = d_in[5];

    const size_t N = (size_t)BATCH * SEQ * D_MODEL;   // 1,048,576
    int*   flag = (int*)d_ws;
    float* Q = (float*)((char*)d_ws + 256);
    float* K = Q + N;
    float* V = K + N;
    float* A = Q;   // alias: each attn block reads only its own Q rows first

    detect_kernel<<<dim3(1), dim3(64), 0, stream>>>((const unsigned short*)wq, flag);
    qkv_kernel<<<dim3(BATCH * SEQ / RROWS), dim3(128), 0, stream>>>(seq, emb, wq, wk, wv, Q, K, V, flag);
    attn_kernel<<<dim3(BATCH * NUM_HEAD, SEQ / QTILE), dim3(512), 0, stream>>>(Q, K, V, A);
    out_proj_kernel<<<dim3(BATCH * SEQ / RROWS), dim3(128), 0, stream>>>(A, wo, d_out, flag);
}

// Round 10
// 846.814 us; speedup vs baseline: 2.7182x; 2.7182x over previous
//
#include <hip/hip_runtime.h>
#include <hip/hip_bf16.h>
#include <cmath>

#define D_MODEL 128
#define NUM_HEAD 4
#define HEAD_DIM 32
#define SEQ 4096
#define BATCH 2
#define QTILE 64   // q-rows per tile (one per lane, G=1 -> no spill)
#define NW 8       // waves per attention block (k-split factor)
#define CHUNK 8    // k's per softmax-rescale chunk; (qt+1)*8 divisible by 8
#define RROWS 32   // token rows per projection block

__device__ __forceinline__ float tof(float x) { return x; }
__device__ __forceinline__ float tof(__hip_bfloat16 x) { return __bfloat162float(x); }
__device__ __forceinline__ void storef(float* p, size_t i, float v) { p[i] = v; }
__device__ __forceinline__ void storef(__hip_bfloat16* p, size_t i, float v) { p[i] = __float2bfloat16(v); }
__device__ __forceinline__ float4 load4(const float* p) { return *(const float4*)p; }
__device__ __forceinline__ float4 load4(const __hip_bfloat16* p) {
    return make_float4(tof(p[0]), tof(p[1]), tof(p[2]), tof(p[3]));
}

// ---------------------------------------------------------------------------
// Kernel 0: dtype detector (f32 vs bf16 inputs), unchanged (passes since R3).
// ---------------------------------------------------------------------------
__global__ void detect_kernel(const unsigned short* __restrict__ w, int* __restrict__ flag)
{
    const int t = threadIdx.x;   // 64 threads
    int weird = 0;
#pragma unroll
    for (int j = 0; j < 4; ++j) {
        const unsigned short v = w[(t * 4 + j) * 2 + 1];
        const float x = __uint_as_float((unsigned)v << 16);
        const float a = fabsf(x);
        if (a > 1e20f || (a > 0.f && a < 1e-20f)) weird++;
    }
#pragma unroll
    for (int off = 32; off; off >>= 1) weird += __shfl_xor(weird, off);
    if (t == 0) *flag = (weird < 32) ? 1 : 0;
}

// ---------------------------------------------------------------------------
// Kernel 1: x = embedding[seq] + PE;  Q/K/V = x @ W^T  (f32 to workspace)
// ---------------------------------------------------------------------------
template <typename T>
__device__ __forceinline__ void qkv_body(
    const int* __restrict__ seq, const T* __restrict__ emb,
    const T* __restrict__ wq, const T* __restrict__ wk, const T* __restrict__ wv,
    float* __restrict__ Q, float* __restrict__ K, float* __restrict__ V)
{
    const int e = threadIdx.x;               // 0..127 output dim
    const int r0 = blockIdx.x * RROWS;
    __shared__ __align__(16) float xs[RROWS][D_MODEL];

    // PE by rotation: angle(r) = (s0+r)*inv; rotate (cos,sin) by inv per row.
    {
        const int i = e >> 1;
        const double inv = 1.0 / pow(10000.0, (double)i / 64.0);
        const int s0 = r0 & (SEQ - 1);       // blocks never straddle batch edge
        double c = cos((double)s0 * inv);
        double s = sin((double)s0 * inv);
        const double cd = cos(inv), sd = sin(inv);
        const bool odd = (e & 1);
#pragma unroll 4
        for (int r = 0; r < RROWS; ++r) {
            const float pe = (float)(odd ? c : s);
            xs[r][e] = tof(emb[(size_t)seq[r0 + r] * D_MODEL + e]) + pe;
            const double cn = c * cd - s * sd;
            s = s * cd + c * sd;
            c = cn;
        }
    }
    __syncthreads();

    const T* wqr = wq + e * D_MODEL;
    const T* wkr = wk + e * D_MODEL;
    const T* wvr = wv + e * D_MODEL;
    float aq[RROWS], ak[RROWS], av[RROWS];
#pragma unroll
    for (int r = 0; r < RROWS; ++r) { aq[r] = 0.f; ak[r] = 0.f; av[r] = 0.f; }

    for (int c = 0; c < 32; ++c) {
        const float4 wq4 = load4(wqr + 4 * c);
        const float4 wk4 = load4(wkr + 4 * c);
        const float4 wv4 = load4(wvr + 4 * c);
#pragma unroll
        for (int r = 0; r < RROWS; ++r) {
            const float4 x4 = *(const float4*)&xs[r][4*c];   // wave-uniform broadcast
            aq[r] += x4.x*wq4.x + x4.y*wq4.y + x4.z*wq4.z + x4.w*wq4.w;
            ak[r] += x4.x*wk4.x + x4.y*wk4.y + x4.z*wk4.z + x4.w*wk4.w;
            av[r] += x4.x*wv4.x + x4.y*wv4.y + x4.z*wv4.z + x4.w*wv4.w;
        }
    }
#pragma unroll
    for (int r = 0; r < RROWS; ++r) {
        const size_t o = (size_t)(r0 + r) * D_MODEL + e;
        Q[o] = aq[r]; K[o] = ak[r]; V[o] = av[r];
    }
}

__global__ __launch_bounds__(128) void qkv_kernel(
    const int* __restrict__ seq, const void* emb,
    const void* wq, const void* wk, const void* wv,
    float* __restrict__ Q, float* __restrict__ K, float* __restrict__ V,
    const int* __restrict__ flag)
{
    if (*flag)
        qkv_body<float>(seq, (const float*)emb, (const float*)wq,
                        (const float*)wk, (const float*)wv, Q, K, V);
    else
        qkv_body<__hip_bfloat16>(seq, (const __hip_bfloat16*)emb, (const __hip_bfloat16*)wq,
                                 (const __hip_bfloat16*)wk, (const __hip_bfloat16*)wv, Q, K, V);
}

// ---------------------------------------------------------------------------
// Kernel 2: attention, G=1 (qv[32], ov[32], m, l per lane). K/V rows via VMEM
// broadcast float4 (opaque-zero-tainted pointer prevents s_load regression).
// R10: unpaired 512-block grid (2 blocks/CU -> 4 waves/SIMD) with
// launch_bounds(512,2) — the empirically verified 128-VGPR no-spill config
// (R9's (512,4) capped VGPRs at 64 -> 3.8GB spill traffic). Pairing map:
// qt = (by<32) ? 63-by : by-32, so round-robin CU c hosts blocks with
// qt = 63-c/8 and c/8 — constant per-CU work. bh on fast axis (XCD L2).
// ---------------------------------------------------------------------------
__device__ __forceinline__ void attn_tile(
    int qt, int wid, int lane, int tid,
    const float* __restrict__ Qh, const float* __restrict__ Kh,
    const float* __restrict__ Vh, float* __restrict__ Oh,
    float (*part)[QTILE][10])
{
    const int row = qt * QTILE + lane;

    float qv[32];
#pragma unroll
    for (int j4 = 0; j4 < 8; ++j4) {
        const float4 a = *(const float4*)(Qh + (size_t)row * HEAD_DIM + 4 * j4);
        qv[4*j4] = a.x; qv[4*j4+1] = a.y; qv[4*j4+2] = a.z; qv[4*j4+3] = a.w;
    }

    float ov[32];
#pragma unroll
    for (int j = 0; j < 32; ++j) ov[j] = 0.f;
    float m = 0.f, l = 0.f;
    const float scale = 0.17677669529663687f;   // 1/sqrt(32)

    const int share = (qt + 1) * (QTILE / NW);  // = (qt+1)*8, multiple of CHUNK
    const int kbeg  = wid * share;
    const int kend  = kbeg + share;

    for (int k0 = kbeg; k0 < kend; k0 += CHUNK) {
        float p[CHUNK];
        float cm = m;
#pragma unroll
        for (int i = 0; i < CHUNK; ++i) {
            const int k = k0 + i;
            const float* kr = Kh + (size_t)k * HEAD_DIM;
            float sc = 0.f;
#pragma unroll
            for (int j4 = 0; j4 < 8; ++j4) {
                const float4 kk = *(const float4*)(kr + 4 * j4);
                sc += qv[4*j4]*kk.x + qv[4*j4+1]*kk.y + qv[4*j4+2]*kk.z + qv[4*j4+3]*kk.w;
            }
            sc = fabsf(sc) * scale;
            p[i] = (k <= row) ? sc : -1.f;      // causal mask (head-space)
            cm = fmaxf(cm, p[i]);
        }
        const float alpha = __expf(m - cm);     // == 1 when max unchanged
        l *= alpha; m = cm;
#pragma unroll
        for (int j = 0; j < 32; ++j) ov[j] *= alpha;
#pragma unroll
        for (int i = 0; i < CHUNK; ++i) {
            const int k = k0 + i;
            const float* vr = Vh + (size_t)k * HEAD_DIM;
            const float e0 = (p[i] >= 0.f) ? __expf(p[i] - m) : 0.f;
            l += e0;
#pragma unroll
            for (int j4 = 0; j4 < 8; ++j4) {
                const float4 vv = *(const float4*)(vr + 4 * j4);
                ov[4*j4]   += e0 * vv.x; ov[4*j4+1] += e0 * vv.y;
                ov[4*j4+2] += e0 * vv.z; ov[4*j4+3] += e0 * vv.w;
            }
        }
    }

    // combine the 8 per-wave partials; 4 passes of 8 dims; LDS = 20.5KB
#pragma unroll
    for (int pass = 0; pass < 4; ++pass) {
        __syncthreads();
#pragma unroll
        for (int j = 0; j < 8; ++j) part[wid][lane][j] = ov[pass * 8 + j];
        part[wid][lane][8] = m;
        part[wid][lane][9] = l;
        __syncthreads();
        {
            const int r = tid >> 3;        // 0..63
            const int j = tid & 7;
            float M = 0.f;
#pragma unroll
            for (int w = 0; w < NW; ++w) M = fmaxf(M, part[w][r][8]);
            float lsum = 0.f, osum = 0.f;
#pragma unroll
            for (int w = 0; w < NW; ++w) {
                const float a = __expf(part[w][r][8] - M);
                lsum += a * part[w][r][9];
                osum += a * part[w][r][j];
            }
            Oh[(size_t)(qt * QTILE + r) * HEAD_DIM + pass * 8 + j] = osum / lsum;
        }
    }
}

__global__ __launch_bounds__(512, 2) void attn_kernel(
    const float* __restrict__ Q, const float* __restrict__ K,
    const float* __restrict__ V, float* __restrict__ O)
{
    const int bh = blockIdx.x;              // fast axis -> XCD = bh
    const int by = blockIdx.y;              // 0..63
    const int qt = (by < 32) ? (63 - by) : (by - 32);   // CU-paired balance
    const size_t base = (size_t)(bh >> 2) * SEQ * D_MODEL + (size_t)(bh & 3) * SEQ * HEAD_DIM;
    const float* Qh = Q + base;
    float*       Oh = O + base;

    int lzero;                               // opaque 0 in a VGPR
    asm volatile("v_mov_b32 %0, 0" : "=v"(lzero));
    const float* Kh = K + base + lzero;      // VGPR-tainted -> VMEM loads
    const float* Vh = V + base + lzero;

    const int tid  = threadIdx.x;
    const int wid  = __builtin_amdgcn_readfirstlane(tid >> 6);
    const int lane = tid & 63;

    __shared__ float part[NW][QTILE][10];

    attn_tile(qt, wid, lane, tid, Qh, Kh, Vh, Oh, part);
}

// ---------------------------------------------------------------------------
// Kernel 3: out = att @ Wo^T  (32-row weight reuse, float4 weight loads)
// ---------------------------------------------------------------------------
template <typename T>
__device__ __forceinline__ void out_proj_body(
    const float* __restrict__ att, const T* __restrict__ wo, T* __restrict__ out)
{
    const int e = threadIdx.x;
    const int r0 = blockIdx.x * RROWS;
    __shared__ __align__(16) float xs[RROWS][D_MODEL];
#pragma unroll 4
    for (int r = 0; r < RROWS; ++r)
        xs[r][e] = att[(size_t)(r0 + r) * D_MODEL + e];
    __syncthreads();

    const T* wr = wo + e * D_MODEL;
    float acc[RROWS];
#pragma unroll
    for (int r = 0; r < RROWS; ++r) acc[r] = 0.f;
    for (int c = 0; c < 32; ++c) {
        const float4 w4 = load4(wr + 4 * c);
#pragma unroll
        for (int r = 0; r < RROWS; ++r) {
            const float4 x4 = *(const float4*)&xs[r][4*c];
            acc[r] += x4.x*w4.x + x4.y*w4.y + x4.z*w4.z + x4.w*w4.w;
        }
    }
#pragma unroll
    for (int r = 0; r < RROWS; ++r)
        storef(out, (size_t)(r0 + r) * D_MODEL + e, acc[r]);
}

__global__ __launch_bounds__(128) void out_proj_kernel(
    const float* __restrict__ att, const void* wo, void* out,
    const int* __restrict__ flag)
{
    if (*flag)
        out_proj_body<float>(att, (const float*)wo, (float*)out);
    else
        out_proj_body<__hip_bfloat16>(att, (const __hip_bfloat16*)wo, (__hip_bfloat16*)out);
}

extern "C" void kernel_launch(void* const* d_in, const int* in_sizes, int n_in,
                              void* d_out, int out_size, void* d_ws, size_t ws_size,
                              hipStream_t stream) {
    const int* seq = (const int*)d_in[0];
    const void* emb = d_in[1];
    const void* wq  = d_in[2];
    const void* wk  = d_in[3];
    const void* wv  = d_in[4];
    const void* wo  = d_in[5];

    const size_t N = (size_t)BATCH * SEQ * D_MODEL;   // 1,048,576
    int*   flag = (int*)d_ws;
    float* Q = (float*)((char*)d_ws + 256);
    float* K = Q + N;
    float* V = K + N;
    float* A = Q;   // alias: each attn block reads only its own Q rows first

    detect_kernel<<<dim3(1), dim3(64), 0, stream>>>((const unsigned short*)wq, flag);
    qkv_kernel<<<dim3(BATCH * SEQ / RROWS), dim3(128), 0, stream>>>(seq, emb, wq, wk, wv, Q, K, V, flag);
    attn_kernel<<<dim3(BATCH * NUM_HEAD, SEQ / QTILE), dim3(512), 0, stream>>>(Q, K, V, A);
    out_proj_kernel<<<dim3(BATCH * SEQ / RROWS), dim3(128), 0, stream>>>(A, wo, d_out, flag);
}

// Round 11
// 382.547 us; speedup vs baseline: 6.0171x; 2.2136x over previous
//
#include <hip/hip_runtime.h>
#include <hip/hip_bf16.h>
#include <cmath>

#define D_MODEL 128
#define NUM_HEAD 4
#define HEAD_DIM 32
#define SEQ 4096
#define BATCH 2
#define QTILE 64   // q-rows per tile (one per lane)
#define NW 8       // waves per attention block (k-split factor)
#define CHUNK 8    // k-rows per staged chunk; (qt+1)*8 divisible by 8
#define RROWS 8    // token rows per projection block (more blocks -> more TLP)

__device__ __forceinline__ float tof(float x) { return x; }
__device__ __forceinline__ float tof(__hip_bfloat16 x) { return __bfloat162float(x); }
__device__ __forceinline__ void storef(float* p, size_t i, float v) { p[i] = v; }
__device__ __forceinline__ void storef(__hip_bfloat16* p, size_t i, float v) { p[i] = __float2bfloat16(v); }
__device__ __forceinline__ float4 load4(const float* p) { return *(const float4*)p; }
__device__ __forceinline__ float4 load4(const __hip_bfloat16* p) {
    return make_float4(tof(p[0]), tof(p[1]), tof(p[2]), tof(p[3]));
}

// ---------------------------------------------------------------------------
// Kernel 0: dtype detector (f32 vs bf16 inputs), unchanged (passes since R3).
// ---------------------------------------------------------------------------
__global__ void detect_kernel(const unsigned short* __restrict__ w, int* __restrict__ flag)
{
    const int t = threadIdx.x;   // 64 threads
    int weird = 0;
#pragma unroll
    for (int j = 0; j < 4; ++j) {
        const unsigned short v = w[(t * 4 + j) * 2 + 1];
        const float x = __uint_as_float((unsigned)v << 16);
        const float a = fabsf(x);
        if (a > 1e20f || (a > 0.f && a < 1e-20f)) weird++;
    }
#pragma unroll
    for (int off = 32; off; off >>= 1) weird += __shfl_xor(weird, off);
    if (t == 0) *flag = (weird < 32) ? 1 : 0;
}

// ---------------------------------------------------------------------------
// Kernel 1: x = embedding[seq] + PE;  Q/K/V = x @ W^T  (f32 to workspace)
// RROWS=8: 1024 blocks -> 2 waves/SIMD (R10's 512x2w gave only 1/SIMD).
// ---------------------------------------------------------------------------
template <typename T>
__device__ __forceinline__ void qkv_body(
    const int* __restrict__ seq, const T* __restrict__ emb,
    const T* __restrict__ wq, const T* __restrict__ wk, const T* __restrict__ wv,
    float* __restrict__ Q, float* __restrict__ K, float* __restrict__ V)
{
    const int e = threadIdx.x;               // 0..127 output dim
    const int r0 = blockIdx.x * RROWS;
    __shared__ __align__(16) float xs[RROWS][D_MODEL];

    // PE by rotation: angle(r) = (s0+r)*inv
    {
        const int i = e >> 1;
        const double inv = 1.0 / pow(10000.0, (double)i / 64.0);
        const int s0 = r0 & (SEQ - 1);       // blocks never straddle batch edge
        double c = cos((double)s0 * inv);
        double s = sin((double)s0 * inv);
        const double cd = cos(inv), sd = sin(inv);
        const bool odd = (e & 1);
#pragma unroll
        for (int r = 0; r < RROWS; ++r) {
            const float pe = (float)(odd ? c : s);
            xs[r][e] = tof(emb[(size_t)seq[r0 + r] * D_MODEL + e]) + pe;
            const double cn = c * cd - s * sd;
            s = s * cd + c * sd;
            c = cn;
        }
    }
    __syncthreads();

    const T* wqr = wq + e * D_MODEL;
    const T* wkr = wk + e * D_MODEL;
    const T* wvr = wv + e * D_MODEL;
    float aq[RROWS], ak[RROWS], av[RROWS];
#pragma unroll
    for (int r = 0; r < RROWS; ++r) { aq[r] = 0.f; ak[r] = 0.f; av[r] = 0.f; }

    for (int c = 0; c < 32; ++c) {
        const float4 wq4 = load4(wqr + 4 * c);
        const float4 wk4 = load4(wkr + 4 * c);
        const float4 wv4 = load4(wvr + 4 * c);
#pragma unroll
        for (int r = 0; r < RROWS; ++r) {
            const float4 x4 = *(const float4*)&xs[r][4*c];   // wave-uniform broadcast
            aq[r] += x4.x*wq4.x + x4.y*wq4.y + x4.z*wq4.z + x4.w*wq4.w;
            ak[r] += x4.x*wk4.x + x4.y*wk4.y + x4.z*wk4.z + x4.w*wk4.w;
            av[r] += x4.x*wv4.x + x4.y*wv4.y + x4.z*wv4.z + x4.w*wv4.w;
        }
    }
#pragma unroll
    for (int r = 0; r < RROWS; ++r) {
        const size_t o = (size_t)(r0 + r) * D_MODEL + e;
        Q[o] = aq[r]; K[o] = ak[r]; V[o] = av[r];
    }
}

__global__ __launch_bounds__(128) void qkv_kernel(
    const int* __restrict__ seq, const void* emb,
    const void* wq, const void* wk, const void* wv,
    float* __restrict__ Q, float* __restrict__ K, float* __restrict__ V,
    const int* __restrict__ flag)
{
    if (*flag)
        qkv_body<float>(seq, (const float*)emb, (const float*)wq,
                        (const float*)wk, (const float*)wv, Q, K, V);
    else
        qkv_body<__hip_bfloat16>(seq, (const __hip_bfloat16*)emb, (const __hip_bfloat16*)wq,
                                 (const __hip_bfloat16*)wk, (const __hip_bfloat16*)wv, Q, K, V);
}

// ---------------------------------------------------------------------------
// Kernel 2: attention with PER-WAVE LDS STAGING (R11).
// R10 post-mortem: 128 broadcast VMEM loads/chunk vs ~9 in flight at ~250cyc
// L2 latency -> load-issue bound (VALUBusy 20%). Now each wave stages its
// 8-k-row chunk (K 1KB + V 1KB) into a private LDS slice: lanes 0..31 load K
// (2 coalesced dwordx4 each), lanes 32..63 load V, prefetched one chunk
// ahead (full compute phase to land). Compute reads are wave-uniform
// ds_read_b128 broadcasts (conflict-free, LDS pipe overlaps VALU).
// 2 VMEM instr/chunk vs 128. No __syncthreads in K-loop (wave owns slice;
// same-wave LDS ops are program-ordered). G=1, launch_bounds(512,2) ->
// 128 VGPR, no spill (R8/R10-verified). Grid: bh fast (XCD L2 locality),
// qt CU-paired big+small. Combine via 20.5KB LDS as before.
// ---------------------------------------------------------------------------
__global__ __launch_bounds__(512, 2) void attn_kernel(
    const float* __restrict__ Q, const float* __restrict__ K,
    const float* __restrict__ V, float* __restrict__ O)
{
    const int bh = blockIdx.x;              // fast axis -> XCD = bh
    const int by = blockIdx.y;              // 0..63
    const int qt = (by < 32) ? (63 - by) : (by - 32);   // CU-paired balance
    const size_t base = (size_t)(bh >> 2) * SEQ * D_MODEL + (size_t)(bh & 3) * SEQ * HEAD_DIM;
    const float* Qh = Q + base;
    const float* Kh = K + base;
    const float* Vh = V + base;
    float*       Oh = O + base;

    const int tid  = threadIdx.x;
    const int wid  = __builtin_amdgcn_readfirstlane(tid >> 6);
    const int lane = tid & 63;
    const int row  = qt * QTILE + lane;

    __shared__ __align__(16) float stage[NW][2 * CHUNK * HEAD_DIM];  // K[8][32] | V[8][32] per wave
    __shared__ float part[NW][QTILE][10];

    float qv[32];
#pragma unroll
    for (int j4 = 0; j4 < 8; ++j4) {
        const float4 a = *(const float4*)(Qh + (size_t)row * HEAD_DIM + 4 * j4);
        qv[4*j4] = a.x; qv[4*j4+1] = a.y; qv[4*j4+2] = a.z; qv[4*j4+3] = a.w;
    }

    float ov[32];
#pragma unroll
    for (int j = 0; j < 32; ++j) ov[j] = 0.f;
    float m = 0.f, l = 0.f;
    const float scale = 0.17677669529663687f;   // 1/sqrt(32)

    const int share = (qt + 1) * (QTILE / NW);  // per-wave k-rows, mult of CHUNK
    const int kbeg  = wid * share;
    const int kend  = kbeg + share;

    // staging roles: lanes 0..31 -> K, lanes 32..63 -> V; 32B (8 floats) each
    const int sl = lane & 31;
    const float* gsrc0 = (lane < 32) ? Kh : Vh;          // + k*32 per chunk
    float* dst = &stage[wid][((lane >= 32) ? CHUNK * HEAD_DIM : 0) + sl * 8];

    // prefetch first chunk
    float4 pa, pb;
    {
        const float* src = gsrc0 + (size_t)kbeg * HEAD_DIM + sl * 8;
        pa = *(const float4*)(src);
        pb = *(const float4*)(src + 4);
    }

    for (int k0 = kbeg; k0 < kend; k0 += CHUNK) {
        // commit staged chunk to LDS
        *(float4*)(dst)     = pa;
        *(float4*)(dst + 4) = pb;
        // prefetch next chunk (lands during compute below)
        if (k0 + CHUNK < kend) {
            const float* src = gsrc0 + (size_t)(k0 + CHUNK) * HEAD_DIM + sl * 8;
            pa = *(const float4*)(src);
            pb = *(const float4*)(src + 4);
        }

        // ---- QK phase (wave-uniform broadcast LDS reads) ----
        float p[CHUNK];
        float cm = m;
#pragma unroll
        for (int i = 0; i < CHUNK; ++i) {
            const float* kr = &stage[wid][i * HEAD_DIM];
            float sc = 0.f;
#pragma unroll
            for (int j4 = 0; j4 < 8; ++j4) {
                const float4 kk = *(const float4*)(kr + 4 * j4);
                sc += qv[4*j4]*kk.x + qv[4*j4+1]*kk.y + qv[4*j4+2]*kk.z + qv[4*j4+3]*kk.w;
            }
            sc = fabsf(sc) * scale;
            p[i] = (k0 + i <= row) ? sc : -1.f;   // causal mask (head-space)
            cm = fmaxf(cm, p[i]);
        }
        const float alpha = __expf(m - cm);       // == 1 when max unchanged
        l *= alpha; m = cm;
#pragma unroll
        for (int j = 0; j < 32; ++j) ov[j] *= alpha;

        // ---- PV phase ----
#pragma unroll
        for (int i = 0; i < CHUNK; ++i) {
            const float e0 = (p[i] >= 0.f) ? __expf(p[i] - m) : 0.f;
            l += e0;
            const float* vr = &stage[wid][CHUNK * HEAD_DIM + i * HEAD_DIM];
#pragma unroll
            for (int j4 = 0; j4 < 8; ++j4) {
                const float4 vv = *(const float4*)(vr + 4 * j4);
                ov[4*j4]   += e0 * vv.x; ov[4*j4+1] += e0 * vv.y;
                ov[4*j4+2] += e0 * vv.z; ov[4*j4+3] += e0 * vv.w;
            }
        }
    }

    // combine the 8 per-wave partials; 4 passes of 8 dims; LDS = 20.5KB
#pragma unroll
    for (int pass = 0; pass < 4; ++pass) {
        __syncthreads();
#pragma unroll
        for (int j = 0; j < 8; ++j) part[wid][lane][j] = ov[pass * 8 + j];
        part[wid][lane][8] = m;
        part[wid][lane][9] = l;
        __syncthreads();
        {
            const int r = tid >> 3;        // 0..63
            const int j = tid & 7;
            float M = 0.f;
#pragma unroll
            for (int w = 0; w < NW; ++w) M = fmaxf(M, part[w][r][8]);
            float lsum = 0.f, osum = 0.f;
#pragma unroll
            for (int w = 0; w < NW; ++w) {
                const float a = __expf(part[w][r][8] - M);
                lsum += a * part[w][r][9];
                osum += a * part[w][r][j];
            }
            Oh[(size_t)(qt * QTILE + r) * HEAD_DIM + pass * 8 + j] = osum / lsum;
        }
    }
}

// ---------------------------------------------------------------------------
// Kernel 3: out = att @ Wo^T  (RROWS=8, float4 weight loads)
// ---------------------------------------------------------------------------
template <typename T>
__device__ __forceinline__ void out_proj_body(
    const float* __restrict__ att, const T* __restrict__ wo, T* __restrict__ out)
{
    const int e = threadIdx.x;
    const int r0 = blockIdx.x * RROWS;
    __shared__ __align__(16) float xs[RROWS][D_MODEL];
#pragma unroll
    for (int r = 0; r < RROWS; ++r)
        xs[r][e] = att[(size_t)(r0 + r) * D_MODEL + e];
    __syncthreads();

    const T* wr = wo + e * D_MODEL;
    float acc[RROWS];
#pragma unroll
    for (int r = 0; r < RROWS; ++r) acc[r] = 0.f;
    for (int c = 0; c < 32; ++c) {
        const float4 w4 = load4(wr + 4 * c);
#pragma unroll
        for (int r = 0; r < RROWS; ++r) {
            const float4 x4 = *(const float4*)&xs[r][4*c];
            acc[r] += x4.x*w4.x + x4.y*w4.y + x4.z*w4.z + x4.w*w4.w;
        }
    }
#pragma unroll
    for (int r = 0; r < RROWS; ++r)
        storef(out, (size_t)(r0 + r) * D_MODEL + e, acc[r]);
}

__global__ __launch_bounds__(128) void out_proj_kernel(
    const float* __restrict__ att, const void* wo, void* out,
    const int* __restrict__ flag)
{
    if (*flag)
        out_proj_body<float>(att, (const float*)wo, (float*)out);
    else
        out_proj_body<__hip_bfloat16>(att, (const __hip_bfloat16*)wo, (__hip_bfloat16*)out);
}

extern "C" void kernel_launch(void* const* d_in, const int* in_sizes, int n_in,
                              void* d_out, int out_size, void* d_ws, size_t ws_size,
                              hipStream_t stream) {
    const int* seq = (const int*)d_in[0];
    const void* emb = d_in[1];
    const void* wq  = d_in[2];
    const void* wk  = d_in[3];
    const void* wv  = d_in[4];
    const void* wo  = d_in[5];

    const size_t N = (size_t)BATCH * SEQ * D_MODEL;   // 1,048,576
    int*   flag = (int*)d_ws;
    float* Q = (float*)((char*)d_ws + 256);
    float* K = Q + N;
    float* V = K + N;
    float* A = Q;   // alias: each attn block reads only its own Q rows first

    detect_kernel<<<dim3(1), dim3(64), 0, stream>>>((const unsigned short*)wq, flag);
    qkv_kernel<<<dim3(BATCH * SEQ / RROWS), dim3(128), 0, stream>>>(seq, emb, wq, wk, wv, Q, K, V, flag);
    attn_kernel<<<dim3(BATCH * NUM_HEAD, SEQ / QTILE), dim3(512), 0, stream>>>(Q, K, V, A);
    out_proj_kernel<<<dim3(BATCH * SEQ / RROWS), dim3(128), 0, stream>>>(A, wo, d_out, flag);
}

// Round 12
// 335.465 us; speedup vs baseline: 6.8616x; 1.1403x over previous
//
#include <hip/hip_runtime.h>
#include <hip/hip_bf16.h>
#include <cmath>

#define D_MODEL 128
#define NUM_HEAD 4
#define HEAD_DIM 32
#define SEQ 4096
#define BATCH 2
#define QTILE 64   // q-rows per tile (one per lane)
#define NW 8       // waves per attention block (k-split factor)
#define CHUNK 8    // k-rows per staged chunk; (qt+1)*8 divisible by 8
#define RROWS 8    // token rows per projection block

__device__ __forceinline__ float tof(float x) { return x; }
__device__ __forceinline__ float tof(__hip_bfloat16 x) { return __bfloat162float(x); }
__device__ __forceinline__ void storef(float* p, size_t i, float v) { p[i] = v; }
__device__ __forceinline__ void storef(__hip_bfloat16* p, size_t i, float v) { p[i] = __float2bfloat16(v); }
__device__ __forceinline__ float4 load4(const float* p) { return *(const float4*)p; }
__device__ __forceinline__ float4 load4(const __hip_bfloat16* p) {
    return make_float4(tof(p[0]), tof(p[1]), tof(p[2]), tof(p[3]));
}

// ---------------------------------------------------------------------------
// Kernel 0: dtype detector (f32 vs bf16 inputs), unchanged (passes since R3).
// ---------------------------------------------------------------------------
__global__ void detect_kernel(const unsigned short* __restrict__ w, int* __restrict__ flag)
{
    const int t = threadIdx.x;   // 64 threads
    int weird = 0;
#pragma unroll
    for (int j = 0; j < 4; ++j) {
        const unsigned short v = w[(t * 4 + j) * 2 + 1];
        const float x = __uint_as_float((unsigned)v << 16);
        const float a = fabsf(x);
        if (a > 1e20f || (a > 0.f && a < 1e-20f)) weird++;
    }
#pragma unroll
    for (int off = 32; off; off >>= 1) weird += __shfl_xor(weird, off);
    if (t == 0) *flag = (weird < 32) ? 1 : 0;
}

// ---------------------------------------------------------------------------
// Kernel 1: x = embedding[seq] + PE;  Q/K/V = x @ W^T  (f32 to workspace)
// ---------------------------------------------------------------------------
template <typename T>
__device__ __forceinline__ void qkv_body(
    const int* __restrict__ seq, const T* __restrict__ emb,
    const T* __restrict__ wq, const T* __restrict__ wk, const T* __restrict__ wv,
    float* __restrict__ Q, float* __restrict__ K, float* __restrict__ V)
{
    const int e = threadIdx.x;               // 0..127 output dim
    const int r0 = blockIdx.x * RROWS;
    __shared__ __align__(16) float xs[RROWS][D_MODEL];

    // PE by rotation: angle(r) = (s0+r)*inv
    {
        const int i = e >> 1;
        const double inv = 1.0 / pow(10000.0, (double)i / 64.0);
        const int s0 = r0 & (SEQ - 1);       // blocks never straddle batch edge
        double c = cos((double)s0 * inv);
        double s = sin((double)s0 * inv);
        const double cd = cos(inv), sd = sin(inv);
        const bool odd = (e & 1);
#pragma unroll
        for (int r = 0; r < RROWS; ++r) {
            const float pe = (float)(odd ? c : s);
            xs[r][e] = tof(emb[(size_t)seq[r0 + r] * D_MODEL + e]) + pe;
            const double cn = c * cd - s * sd;
            s = s * cd + c * sd;
            c = cn;
        }
    }
    __syncthreads();

    const T* wqr = wq + e * D_MODEL;
    const T* wkr = wk + e * D_MODEL;
    const T* wvr = wv + e * D_MODEL;
    float aq[RROWS], ak[RROWS], av[RROWS];
#pragma unroll
    for (int r = 0; r < RROWS; ++r) { aq[r] = 0.f; ak[r] = 0.f; av[r] = 0.f; }

    for (int c = 0; c < 32; ++c) {
        const float4 wq4 = load4(wqr + 4 * c);
        const float4 wk4 = load4(wkr + 4 * c);
        const float4 wv4 = load4(wvr + 4 * c);
#pragma unroll
        for (int r = 0; r < RROWS; ++r) {
            const float4 x4 = *(const float4*)&xs[r][4*c];   // wave-uniform broadcast
            aq[r] += x4.x*wq4.x + x4.y*wq4.y + x4.z*wq4.z + x4.w*wq4.w;
            ak[r] += x4.x*wk4.x + x4.y*wk4.y + x4.z*wk4.z + x4.w*wk4.w;
            av[r] += x4.x*wv4.x + x4.y*wv4.y + x4.z*wv4.z + x4.w*wv4.w;
        }
    }
#pragma unroll
    for (int r = 0; r < RROWS; ++r) {
        const size_t o = (size_t)(r0 + r) * D_MODEL + e;
        Q[o] = aq[r]; K[o] = ak[r]; V[o] = av[r];
    }
}

__global__ __launch_bounds__(128) void qkv_kernel(
    const int* __restrict__ seq, const void* emb,
    const void* wq, const void* wk, const void* wv,
    float* __restrict__ Q, float* __restrict__ K, float* __restrict__ V,
    const int* __restrict__ flag)
{
    if (*flag)
        qkv_body<float>(seq, (const float*)emb, (const float*)wq,
                        (const float*)wk, (const float*)wv, Q, K, V);
    else
        qkv_body<__hip_bfloat16>(seq, (const __hip_bfloat16*)emb, (const __hip_bfloat16*)wq,
                                 (const __hip_bfloat16*)wk, (const __hip_bfloat16*)wv, Q, K, V);
}

// ---------------------------------------------------------------------------
// Kernel 2: attention = R11 per-wave LDS-staging body + R8 perfectly-paired
// grid. R11 post-mortem: 512 unequal blocks -> drain phase; qt=63 block alone
// set the runtime (Occupancy 18%). Now 256 blocks, block by does tiles
// (63-by) then (by): exactly 65 work-units each, 1 block/CU, all CUs finish
// together. Staging: lanes 0..31 stage K chunk, 32..63 stage V chunk into a
// private LDS slice, prefetched one chunk ahead; compute reads are
// wave-uniform ds_read_b128 broadcasts. 2 VMEM instr/chunk. No K-loop
// barriers. launch_bounds(512,2) = the verified 128-VGPR no-spill config.
// ---------------------------------------------------------------------------
__device__ __forceinline__ void attn_tile(
    int qt, int wid, int lane, int tid,
    const float* __restrict__ Qh, const float* __restrict__ Kh,
    const float* __restrict__ Vh, float* __restrict__ Oh,
    float (*stage)[2 * CHUNK * HEAD_DIM], float (*part)[QTILE][10])
{
    const int row = qt * QTILE + lane;

    float qv[32];
#pragma unroll
    for (int j4 = 0; j4 < 8; ++j4) {
        const float4 a = *(const float4*)(Qh + (size_t)row * HEAD_DIM + 4 * j4);
        qv[4*j4] = a.x; qv[4*j4+1] = a.y; qv[4*j4+2] = a.z; qv[4*j4+3] = a.w;
    }

    float ov[32];
#pragma unroll
    for (int j = 0; j < 32; ++j) ov[j] = 0.f;
    float m = 0.f, l = 0.f;
    const float scale = 0.17677669529663687f;   // 1/sqrt(32)

    const int share = (qt + 1) * (QTILE / NW);  // per-wave k-rows, mult of CHUNK
    const int kbeg  = wid * share;
    const int kend  = kbeg + share;

    // staging roles: lanes 0..31 -> K, lanes 32..63 -> V; 32B (8 floats) each
    const int sl = lane & 31;
    const float* gsrc0 = (lane < 32) ? Kh : Vh;
    float* dst = &stage[wid][((lane >= 32) ? CHUNK * HEAD_DIM : 0) + sl * 8];

    // prefetch first chunk
    float4 pa, pb;
    {
        const float* src = gsrc0 + (size_t)kbeg * HEAD_DIM + sl * 8;
        pa = *(const float4*)(src);
        pb = *(const float4*)(src + 4);
    }

    for (int k0 = kbeg; k0 < kend; k0 += CHUNK) {
        // commit staged chunk to LDS
        *(float4*)(dst)     = pa;
        *(float4*)(dst + 4) = pb;
        // prefetch next chunk (lands during compute below)
        if (k0 + CHUNK < kend) {
            const float* src = gsrc0 + (size_t)(k0 + CHUNK) * HEAD_DIM + sl * 8;
            pa = *(const float4*)(src);
            pb = *(const float4*)(src + 4);
        }

        // ---- QK phase (wave-uniform broadcast LDS reads) ----
        float p[CHUNK];
        float cm = m;
#pragma unroll
        for (int i = 0; i < CHUNK; ++i) {
            const float* kr = &stage[wid][i * HEAD_DIM];
            float sc = 0.f;
#pragma unroll
            for (int j4 = 0; j4 < 8; ++j4) {
                const float4 kk = *(const float4*)(kr + 4 * j4);
                sc += qv[4*j4]*kk.x + qv[4*j4+1]*kk.y + qv[4*j4+2]*kk.z + qv[4*j4+3]*kk.w;
            }
            sc = fabsf(sc) * scale;
            p[i] = (k0 + i <= row) ? sc : -1.f;   // causal mask (head-space)
            cm = fmaxf(cm, p[i]);
        }
        const float alpha = __expf(m - cm);       // == 1 when max unchanged
        l *= alpha; m = cm;
#pragma unroll
        for (int j = 0; j < 32; ++j) ov[j] *= alpha;

        // ---- PV phase ----
#pragma unroll
        for (int i = 0; i < CHUNK; ++i) {
            const float e0 = (p[i] >= 0.f) ? __expf(p[i] - m) : 0.f;
            l += e0;
            const float* vr = &stage[wid][CHUNK * HEAD_DIM + i * HEAD_DIM];
#pragma unroll
            for (int j4 = 0; j4 < 8; ++j4) {
                const float4 vv = *(const float4*)(vr + 4 * j4);
                ov[4*j4]   += e0 * vv.x; ov[4*j4+1] += e0 * vv.y;
                ov[4*j4+2] += e0 * vv.z; ov[4*j4+3] += e0 * vv.w;
            }
        }
    }

    // combine the 8 per-wave partials; 4 passes of 8 dims
#pragma unroll
    for (int pass = 0; pass < 4; ++pass) {
        __syncthreads();
#pragma unroll
        for (int j = 0; j < 8; ++j) part[wid][lane][j] = ov[pass * 8 + j];
        part[wid][lane][8] = m;
        part[wid][lane][9] = l;
        __syncthreads();
        {
            const int r = tid >> 3;        // 0..63
            const int j = tid & 7;
            float M = 0.f;
#pragma unroll
            for (int w = 0; w < NW; ++w) M = fmaxf(M, part[w][r][8]);
            float lsum = 0.f, osum = 0.f;
#pragma unroll
            for (int w = 0; w < NW; ++w) {
                const float a = __expf(part[w][r][8] - M);
                lsum += a * part[w][r][9];
                osum += a * part[w][r][j];
            }
            Oh[(size_t)(qt * QTILE + r) * HEAD_DIM + pass * 8 + j] = osum / lsum;
        }
    }
}

__global__ __launch_bounds__(512, 2) void attn_kernel(
    const float* __restrict__ Q, const float* __restrict__ K,
    const float* __restrict__ V, float* __restrict__ O)
{
    const int bh = blockIdx.x;              // fast axis -> XCD = bh (L2 locality)
    const int by = blockIdx.y;              // 0..31
    const size_t base = (size_t)(bh >> 2) * SEQ * D_MODEL + (size_t)(bh & 3) * SEQ * HEAD_DIM;
    const float* Qh = Q + base;
    const float* Kh = K + base;
    const float* Vh = V + base;
    float*       Oh = O + base;

    const int tid  = threadIdx.x;
    const int wid  = __builtin_amdgcn_readfirstlane(tid >> 6);
    const int lane = tid & 63;

    __shared__ __align__(16) float stage[NW][2 * CHUNK * HEAD_DIM];
    __shared__ float part[NW][QTILE][10];

    attn_tile(63 - by, wid, lane, tid, Qh, Kh, Vh, Oh, stage, part);  // work 64-by
    attn_tile(by,      wid, lane, tid, Qh, Kh, Vh, Oh, stage, part);  // work by+1
}

// ---------------------------------------------------------------------------
// Kernel 3: out = att @ Wo^T  (RROWS=8, float4 weight loads)
// ---------------------------------------------------------------------------
template <typename T>
__device__ __forceinline__ void out_proj_body(
    const float* __restrict__ att, const T* __restrict__ wo, T* __restrict__ out)
{
    const int e = threadIdx.x;
    const int r0 = blockIdx.x * RROWS;
    __shared__ __align__(16) float xs[RROWS][D_MODEL];
#pragma unroll
    for (int r = 0; r < RROWS; ++r)
        xs[r][e] = att[(size_t)(r0 + r) * D_MODEL + e];
    __syncthreads();

    const T* wr = wo + e * D_MODEL;
    float acc[RROWS];
#pragma unroll
    for (int r = 0; r < RROWS; ++r) acc[r] = 0.f;
    for (int c = 0; c < 32; ++c) {
        const float4 w4 = load4(wr + 4 * c);
#pragma unroll
        for (int r = 0; r < RROWS; ++r) {
            const float4 x4 = *(const float4*)&xs[r][4*c];
            acc[r] += x4.x*w4.x + x4.y*w4.y + x4.z*w4.z + x4.w*w4.w;
        }
    }
#pragma unroll
    for (int r = 0; r < RROWS; ++r)
        storef(out, (size_t)(r0 + r) * D_MODEL + e, acc[r]);
}

__global__ __launch_bounds__(128) void out_proj_kernel(
    const float* __restrict__ att, const void* wo, void* out,
    const int* __restrict__ flag)
{
    if (*flag)
        out_proj_body<float>(att, (const float*)wo, (float*)out);
    else
        out_proj_body<__hip_bfloat16>(att, (const __hip_bfloat16*)wo, (__hip_bfloat16*)out);
}

extern "C" void kernel_launch(void* const* d_in, const int* in_sizes, int n_in,
                              void* d_out, int out_size, void* d_ws, size_t ws_size,
                              hipStream_t stream) {
    const int* seq = (const int*)d_in[0];
    const void* emb = d_in[1];
    const void* wq  = d_in[2];
    const void* wk  = d_in[3];
    const void* wv  = d_in[4];
    const void* wo  = d_in[5];

    const size_t N = (size_t)BATCH * SEQ * D_MODEL;   // 1,048,576
    int*   flag = (int*)d_ws;
    float* Q = (float*)((char*)d_ws + 256);
    float* K = Q + N;
    float* V = K + N;
    float* A = Q;   // alias: each attn tile reads only its own Q rows first

    detect_kernel<<<dim3(1), dim3(64), 0, stream>>>((const unsigned short*)wq, flag);
    qkv_kernel<<<dim3(BATCH * SEQ / RROWS), dim3(128), 0, stream>>>(seq, emb, wq, wk, wv, Q, K, V, flag);
    attn_kernel<<<dim3(BATCH * NUM_HEAD, SEQ / QTILE / 2), dim3(512), 0, stream>>>(Q, K, V, A);
    out_proj_kernel<<<dim3(BATCH * SEQ / RROWS), dim3(128), 0, stream>>>(A, wo, d_out, flag);
}